// Round 4
// baseline (62.608 us; speedup 1.0000x reference)
//
#include <hip/hip_runtime.h>
#include <hip/hip_bf16.h>
#include <math.h>

#define Bsz 16
#define Nn  128
#define NFd 64
#define NDd 100
#define NHd 64

typedef __attribute__((ext_vector_type(8))) short bf16x8;
typedef __attribute__((ext_vector_type(4))) float f32x4;

__device__ __forceinline__ short f2bf(float f) {
  return (short)__builtin_bit_cast(ushort, __float2bfloat16(f));
}

__device__ __forceinline__ float fast_tanh(float x) {
  // tanh(x) = 1 - 2/(exp(2x)+1); exact at +/-inf, ~1ulp rcp error (<< bf16 noise)
  float e = __expf(2.0f * x);
  return 1.0f - 2.0f * __builtin_amdgcn_rcpf(e + 1.0f);
}

// ---------------- prep kernel ----------------
// blocks [0,512):   atomh[b,j,h] = b_cf[h] + sum_f AF[b,j,f]*W_cf[f,h]   (f32 -> ws)
// blocks [512,544): pack W_df -> bf16 MFMA-B fragments, K zero-padded to 128
// blocks [544,560): pack W_fc -> bf16 MFMA-B fragments (K=64)
__global__ __launch_bounds__(256) void prep_kernel(
    const float* __restrict__ AF, const float* __restrict__ Wcf,
    const float* __restrict__ bcf, const float* __restrict__ Wdf,
    const float* __restrict__ Wfc, float* __restrict__ atomh,
    ushort* __restrict__ wdfp, ushort* __restrict__ wfcp) {
  int t = threadIdx.x;
  int blk = blockIdx.x;
  if (blk < 512) {
    int row = blk * 4 + (t >> 6);        // b*N + j
    int h = t & 63;
    const float* af = AF + (size_t)row * NFd;
    float a0 = 0.f, a1 = 0.f, a2 = 0.f, a3 = 0.f;
    #pragma unroll 4
    for (int f = 0; f < NFd; f += 4) {
      a0 += af[f + 0] * Wcf[(f + 0) * NHd + h];
      a1 += af[f + 1] * Wcf[(f + 1) * NHd + h];
      a2 += af[f + 2] * Wcf[(f + 2) * NHd + h];
      a3 += af[f + 3] * Wcf[(f + 3) * NHd + h];
    }
    atomh[(size_t)row * NHd + h] = bcf[h] + ((a0 + a1) + (a2 + a3));
  } else if (blk < 544) {
    // wdfp[(grp*64 + col)*8 + e] = bf16(Wdf[k = grp*8+e][col]), 0 if k >= 100
    int idx = (blk - 512) * 256 + t;     // [0, 8192)
    int e = idx & 7;
    int col = (idx >> 3) & 63;
    int grp = idx >> 9;
    int k = grp * 8 + e;
    float v = (k < NDd) ? Wdf[k * NHd + col] : 0.f;
    wdfp[idx] = (ushort)f2bf(v);
  } else {
    int idx = (blk - 544) * 256 + t;     // [0, 4096)
    int e = idx & 7;
    int col = (idx >> 3) & 63;
    int grp = idx >> 9;
    int k = grp * 8 + e;
    wfcp[idx] = (ushort)f2bf(Wfc[k * NFd + col]);
  }
}

// ---------------- main kernel: one block per (b,i), 4 waves ----------------
// Wave w exclusively owns j-rows [32w, 32w+32). Per 16-row stripe (jt), run
// phase1 -> gate -> LDS -> phase2 -> tanh-reduce fused, so only one 4x f32x4
// accumulator is live at a time (low VGPR pressure -> high occupancy).
// A-fragments of phase 1 load DIRECTLY from global DM (lane p = row j,
// lane q = k-chunk) and convert f32->bf16 in-register.
__global__ __launch_bounds__(256, 4) void dtnn_main_kernel(
    const float* __restrict__ AF,
    const float* __restrict__ DM,
    const float* __restrict__ MASK,
    const float* __restrict__ bdf,
    const float* __restrict__ atomh,
    const ushort* __restrict__ wdfp,
    const ushort* __restrict__ wfcp,
    float* __restrict__ out) {
  __shared__ ushort gbuf[Nn * 64];     // gated, bf16, XOR-swizzled: [j][h ^ ((j&7)<<3)]
  __shared__ float masklds[Nn];
  __shared__ float red[4 * 64];

  const int t  = threadIdx.x;
  const int bi = blockIdx.x;           // b*N + i
  const int b  = bi >> 7;
  const int w  = t >> 6;               // wave 0..3 -> j rows [32w, 32w+32)
  const int p  = t & 15;               // lane&15
  const int q  = (t >> 4) & 3;         // lane>>4 (within wave)
  const int l  = t & 63;

  // mask for this wave's rows (wave-private LDS region)
  if (l < 32) masklds[w * 32 + l] = MASK[(size_t)bi * Nn + w * 32 + l];

  const float* dmblk = DM + (size_t)bi * (Nn * NDd);
  const bf16x8* wdfv = reinterpret_cast<const bf16x8*>(wdfp);
  const bf16x8* wfcv = reinterpret_cast<const bf16x8*>(wfcp);

  float s[4] = {0.f, 0.f, 0.f, 0.f};

  #pragma unroll 1
  for (int jt = 0; jt < 2; ++jt) {
    const int jrow = (2 * w + jt) * 16;      // this stripe's base row

    // ---- phase 1: dist_h[j,h] = dm[j,:].W_df[:,h] + b_df[h], K=100 ----
    f32x4 acc[4];
    #pragma unroll
    for (int ht = 0; ht < 4; ++ht) {
      float bv = bdf[ht * 16 + p];
      acc[ht] = (f32x4){bv, bv, bv, bv};
    }

    #pragma unroll
    for (int ks = 0; ks < 3; ++ks) {         // k = [0,96)
      const float* rowp = dmblk + (jrow + p) * NDd + ks * 32 + q * 8;
      float4 x = *reinterpret_cast<const float4*>(rowp);
      float4 y = *reinterpret_cast<const float4*>(rowp + 4);
      bf16x8 a;
      a[0] = f2bf(x.x); a[1] = f2bf(x.y); a[2] = f2bf(x.z); a[3] = f2bf(x.w);
      a[4] = f2bf(y.x); a[5] = f2bf(y.y); a[6] = f2bf(y.z); a[7] = f2bf(y.w);
      #pragma unroll
      for (int ht = 0; ht < 4; ++ht) {
        bf16x8 bfr = wdfv[(ks * 4 + q) * 64 + ht * 16 + p];
        acc[ht] = __builtin_amdgcn_mfma_f32_16x16x32_bf16(a, bfr, acc[ht], 0, 0, 0);
      }
    }
    {                                        // tail k = [96,100): only q==0 carries data
      bf16x8 a = (bf16x8){0, 0, 0, 0, 0, 0, 0, 0};
      if (q == 0) {
        float4 x = *reinterpret_cast<const float4*>(dmblk + (jrow + p) * NDd + 96);
        a[0] = f2bf(x.x); a[1] = f2bf(x.y); a[2] = f2bf(x.z); a[3] = f2bf(x.w);
      }
      #pragma unroll
      for (int ht = 0; ht < 4; ++ht) {
        bf16x8 bfr = wdfv[(12 + q) * 64 + ht * 16 + p];
        acc[ht] = __builtin_amdgcn_mfma_f32_16x16x32_bf16(a, bfr, acc[ht], 0, 0, 0);
      }
    }

    // ---- gate: acc[j][h] *= atomh[b,j,h]  (D layout: row j=jrow+4q+r, col h=16ht+p) ----
    const float* ap = atomh + ((size_t)(b * Nn + jrow + 4 * q)) * NHd + p;
    #pragma unroll
    for (int ht = 0; ht < 4; ++ht) {
      #pragma unroll
      for (int r = 0; r < 4; ++r) acc[ht][r] *= ap[r * NHd + ht * 16];
    }

    // ---- write gated (bf16, swizzled) to this wave's stripe ----
    #pragma unroll
    for (int r = 0; r < 4; ++r) {
      int j = jrow + 4 * q + r;
      int sw = (j & 7) << 3;
      #pragma unroll
      for (int ht = 0; ht < 4; ++ht)
        gbuf[j * 64 + ((ht * 16 + p) ^ sw)] = (ushort)f2bf(acc[ht][r]);
    }
    // wave-private LDS stripe: same-wave ds ops are ordered; just stop the
    // compiler from moving the reads above the writes.
    asm volatile("" ::: "memory");

    // ---- phase 2: pre[j,f] = gated[j,:].W_fc[:,f], K=64 (same stripe) ----
    f32x4 acc2[4];
    #pragma unroll
    for (int ft = 0; ft < 4; ++ft) acc2[ft] = (f32x4){0.f, 0.f, 0.f, 0.f};

    #pragma unroll
    for (int ks = 0; ks < 2; ++ks) {
      int j = jrow + p;
      int h0 = ks * 32 + q * 8;
      bf16x8 a2 = *reinterpret_cast<const bf16x8*>(&gbuf[j * 64 + (h0 ^ ((j & 7) << 3))]);
      #pragma unroll
      for (int ft = 0; ft < 4; ++ft) {
        bf16x8 bfr = wfcv[(ks * 4 + q) * 64 + ft * 16 + p];
        acc2[ft] = __builtin_amdgcn_mfma_f32_16x16x32_bf16(a2, bfr, acc2[ft], 0, 0, 0);
      }
    }

    // ---- mask, tanh, accumulate this stripe's 4 rows ----
    #pragma unroll
    for (int r = 0; r < 4; ++r) {
      float m = masklds[jrow + 4 * q + r];
      #pragma unroll
      for (int ft = 0; ft < 4; ++ft) s[ft] += fast_tanh(acc2[ft][r] * m);
    }
  }

  // ---- cross-lane + cross-wave reduce over j ----
  #pragma unroll
  for (int ft = 0; ft < 4; ++ft) {
    s[ft] += __shfl_xor(s[ft], 16, 64);
    s[ft] += __shfl_xor(s[ft], 32, 64);
  }
  if (q == 0) {
    #pragma unroll
    for (int ft = 0; ft < 4; ++ft) red[w * 64 + ft * 16 + p] = s[ft];
  }
  __syncthreads();   // the only cross-wave sync
  if (t < 64) {
    float tot = red[t] + red[64 + t] + red[128 + t] + red[192 + t];
    out[(size_t)bi * NFd + t] = tot + AF[(size_t)bi * NFd + t];
  }
}

extern "C" void kernel_launch(void* const* d_in, const int* in_sizes, int n_in,
                              void* d_out, int out_size, void* d_ws, size_t ws_size,
                              hipStream_t stream) {
  const float* AF   = (const float*)d_in[0];
  const float* DM   = (const float*)d_in[1];
  const float* MASK = (const float*)d_in[2];
  const float* Wcf  = (const float*)d_in[3];
  const float* Wdf  = (const float*)d_in[4];
  const float* Wfc  = (const float*)d_in[5];
  const float* bcf  = (const float*)d_in[6];
  const float* bdf  = (const float*)d_in[7];
  float* out = (float*)d_out;

  float*  atomh = (float*)d_ws;                                   // 512 KB
  ushort* wdfp  = (ushort*)((char*)d_ws + 524288);                // 16 KB (K padded to 128)
  ushort* wfcp  = (ushort*)((char*)d_ws + 524288 + 16384);        // 8 KB

  prep_kernel<<<560, 256, 0, stream>>>(AF, Wcf, bcf, Wdf, Wfc, atomh, wdfp, wfcp);
  dtnn_main_kernel<<<Bsz * Nn, 256, 0, stream>>>(AF, DM, MASK, bdf, atomh, wdfp, wfcp, out);
}

// Round 5
// 41.057 us; speedup vs baseline: 1.5249x; 1.5249x over previous
//
#include <hip/hip_runtime.h>
#include <hip/hip_bf16.h>

#define Bsz 16
#define Nn  128
#define NFd 64
#define NDd 100
#define NHd 64

typedef __attribute__((ext_vector_type(8))) short bf16x8;
typedef __attribute__((ext_vector_type(4))) float f32x4;

__device__ __forceinline__ short f2bf(float f) {
  return (short)__builtin_bit_cast(ushort, __float2bfloat16(f));
}

__device__ __forceinline__ float fast_tanh(float x) {
  // tanh(x) = 1 - 2/(exp(2x)+1); exact at +/-inf, ~1ulp rcp error (<< bf16 noise)
  float e = __expf(2.0f * x);
  return 1.0f - 2.0f * __builtin_amdgcn_rcpf(e + 1.0f);
}

// async global->LDS DMA: LDS dest = uniform base + lane*size; global src per-lane
__device__ __forceinline__ void glds16(const float* g, float* l) {
  __builtin_amdgcn_global_load_lds(
      (const __attribute__((address_space(1))) void*)g,
      (__attribute__((address_space(3))) void*)l, 16, 0, 0);
}
__device__ __forceinline__ void glds4(const float* g, float* l) {
  __builtin_amdgcn_global_load_lds(
      (const __attribute__((address_space(1))) void*)g,
      (__attribute__((address_space(3))) void*)l, 4, 0, 0);
}

// ---------------- prep kernel ----------------
// blocks [0,512):   atomh[b,j,h] = b_cf[h] + sum_f AF[b,j,f]*W_cf[f,h]   (f32 -> ws)
// blocks [512,544): pack W_df -> bf16 MFMA-B fragments, K zero-padded to 128
// blocks [544,560): pack W_fc -> bf16 MFMA-B fragments (K=64)
__global__ __launch_bounds__(256) void prep_kernel(
    const float* __restrict__ AF, const float* __restrict__ Wcf,
    const float* __restrict__ bcf, const float* __restrict__ Wdf,
    const float* __restrict__ Wfc, float* __restrict__ atomh,
    ushort* __restrict__ wdfp, ushort* __restrict__ wfcp) {
  int t = threadIdx.x;
  int blk = blockIdx.x;
  if (blk < 512) {
    int row = blk * 4 + (t >> 6);        // b*N + j
    int h = t & 63;
    const float* af = AF + (size_t)row * NFd;
    float a0 = 0.f, a1 = 0.f, a2 = 0.f, a3 = 0.f;
    #pragma unroll 4
    for (int f = 0; f < NFd; f += 4) {
      a0 += af[f + 0] * Wcf[(f + 0) * NHd + h];
      a1 += af[f + 1] * Wcf[(f + 1) * NHd + h];
      a2 += af[f + 2] * Wcf[(f + 2) * NHd + h];
      a3 += af[f + 3] * Wcf[(f + 3) * NHd + h];
    }
    atomh[(size_t)row * NHd + h] = bcf[h] + ((a0 + a1) + (a2 + a3));
  } else if (blk < 544) {
    // wdfp[(grp*64 + col)*8 + e] = bf16(Wdf[k = grp*8+e][col]), 0 if k >= 100
    int idx = (blk - 512) * 256 + t;     // [0, 8192)
    int e = idx & 7;
    int col = (idx >> 3) & 63;
    int grp = idx >> 9;
    int k = grp * 8 + e;
    float v = (k < NDd) ? Wdf[k * NHd + col] : 0.f;
    wdfp[idx] = (ushort)f2bf(v);
  } else {
    int idx = (blk - 544) * 256 + t;     // [0, 4096)
    int e = idx & 7;
    int col = (idx >> 3) & 63;
    int grp = idx >> 9;
    int k = grp * 8 + e;
    wfcp[idx] = (ushort)f2bf(Wfc[k * NFd + col]);
  }
}

// ---------------- main kernel: one block per (b,i), 4 waves ----------------
// Each wave owns j-rows [32w, 32w+32) end-to-end. DM tile staged f32 into LDS
// via global_load_lds (deep async queue, zero VGPR cost), wave-private region
// -> no barrier, one vmcnt(0). Gated bf16 tile reuses the stripe's own staged
// LDS (ordered by data dependence). K-tail branch-free: ks=3 overreads words
// 100..127 (garbage) which multiply the zero-packed W_df rows k>=100.
__global__ __launch_bounds__(256, 3) void dtnn_main_kernel(
    const float* __restrict__ AF,
    const float* __restrict__ DM,
    const float* __restrict__ MASK,
    const float* __restrict__ bdf,
    const float* __restrict__ atomh,
    const ushort* __restrict__ wdfp,
    const ushort* __restrict__ wfcp,
    float* __restrict__ out) {
  __shared__ float stage[12832];   // 128 rows x 100 f32, linear + 32 f32 pad
  __shared__ float red[256];

  const int t    = threadIdx.x;
  const int bi   = blockIdx.x;           // b*N + i
  const int b    = bi >> 7;
  const int w    = t >> 6;               // wave 0..3 -> j rows [32w, 32w+32)
  const int lane = t & 63;
  const int p    = t & 15;               // lane&15
  const int q    = (t >> 4) & 3;         // lane>>4 (within wave)

  // ---- async-stage this wave's 32 rows (12800 B) linearly into LDS ----
  const float* gsrc = DM + (size_t)bi * (Nn * NDd) + w * 3200;
  float* lbase = stage + w * 3200;
  #pragma unroll
  for (int v = 0; v < 12; ++v)
    glds16(gsrc + v * 256 + lane * 4, lbase + v * 256);   // 12 x 1024 B
  glds4(gsrc + 3072 + lane, lbase + 3072);                // 2 x 256 B tail
  glds4(gsrc + 3136 + lane, lbase + 3136);

  asm volatile("s_waitcnt vmcnt(0)" ::: "memory");
  __builtin_amdgcn_sched_barrier(0);

  const bf16x8* wdfv = reinterpret_cast<const bf16x8*>(wdfp);
  const bf16x8* wfcv = reinterpret_cast<const bf16x8*>(wfcp);

  float s[4] = {0.f, 0.f, 0.f, 0.f};

  #pragma unroll 1
  for (int jt = 0; jt < 2; ++jt) {
    const int jrow = (2 * w + jt) * 16;      // this stripe's base row

    // ---- phase 1: dist_h[j,h] = dm[j,:].W_df[:,h] + b_df[h], K=100 (pad 128) ----
    f32x4 acc[4];
    #pragma unroll
    for (int ht = 0; ht < 4; ++ht) {
      float bv = bdf[ht * 16 + p];
      acc[ht] = (f32x4){bv, bv, bv, bv};
    }

    const float* arow = stage + (jrow + p) * 100;
    #pragma unroll
    for (int ks = 0; ks < 4; ++ks) {
      float4 x = *reinterpret_cast<const float4*>(arow + ks * 32 + q * 8);
      float4 y = *reinterpret_cast<const float4*>(arow + ks * 32 + q * 8 + 4);
      bf16x8 a;
      a[0] = f2bf(x.x); a[1] = f2bf(x.y); a[2] = f2bf(x.z); a[3] = f2bf(x.w);
      a[4] = f2bf(y.x); a[5] = f2bf(y.y); a[6] = f2bf(y.z); a[7] = f2bf(y.w);
      #pragma unroll
      for (int ht = 0; ht < 4; ++ht)
        acc[ht] = __builtin_amdgcn_mfma_f32_16x16x32_bf16(
            a, wdfv[(ks * 4 + q) * 64 + ht * 16 + p], acc[ht], 0, 0, 0);
    }

    // ---- gate: acc[j][h] *= atomh[b,j,h]  (D: row j=jrow+4q+r, col h=16ht+p) ----
    const float* ap = atomh + ((size_t)(b * Nn + jrow + 4 * q)) * NHd + p;
    #pragma unroll
    for (int ht = 0; ht < 4; ++ht) {
      #pragma unroll
      for (int r = 0; r < 4; ++r) acc[ht][r] *= ap[r * NHd + ht * 16];
    }

    // ---- write gated (bf16, XOR-swizzled) over this stripe's own staged rows ----
    ushort* gb = reinterpret_cast<ushort*>(stage + w * 3200 + jt * 1600);
    #pragma unroll
    for (int r = 0; r < 4; ++r) {
      int rr = 4 * q + r;                    // local row 0..15
      int sw = (rr & 7) << 3;
      #pragma unroll
      for (int ht = 0; ht < 4; ++ht)
        gb[rr * 64 + ((ht * 16 + p) ^ sw)] = (ushort)f2bf(acc[ht][r]);
    }
    asm volatile("" ::: "memory");   // don't hoist phase-2 reads above writes

    // ---- phase 2: pre[j,f] = gated[j,:].W_fc[:,f], K=64 ----
    f32x4 acc2[4];
    #pragma unroll
    for (int ft = 0; ft < 4; ++ft) acc2[ft] = (f32x4){0.f, 0.f, 0.f, 0.f};

    #pragma unroll
    for (int ks = 0; ks < 2; ++ks) {
      int h0 = (ks * 32 + q * 8) ^ ((p & 7) << 3);
      bf16x8 a2 = *reinterpret_cast<const bf16x8*>(&gb[p * 64 + h0]);
      #pragma unroll
      for (int ft = 0; ft < 4; ++ft)
        acc2[ft] = __builtin_amdgcn_mfma_f32_16x16x32_bf16(
            a2, wfcv[(ks * 4 + q) * 64 + ft * 16 + p], acc2[ft], 0, 0, 0);
    }

    // ---- mask, tanh, accumulate this stripe's 4 rows ----
    #pragma unroll
    for (int r = 0; r < 4; ++r) {
      float m = MASK[(size_t)bi * Nn + jrow + 4 * q + r];   // uniform over p -> broadcast
      #pragma unroll
      for (int ft = 0; ft < 4; ++ft) s[ft] += fast_tanh(acc2[ft][r] * m);
    }
  }

  // ---- cross-lane + cross-wave reduce over j ----
  #pragma unroll
  for (int ft = 0; ft < 4; ++ft) {
    s[ft] += __shfl_xor(s[ft], 16, 64);
    s[ft] += __shfl_xor(s[ft], 32, 64);
  }
  if (q == 0) {
    #pragma unroll
    for (int ft = 0; ft < 4; ++ft) red[w * 64 + ft * 16 + p] = s[ft];
  }
  __syncthreads();   // the only cross-wave sync
  if (t < 64) {
    float tot = red[t] + red[64 + t] + red[128 + t] + red[192 + t];
    out[(size_t)bi * NFd + t] = tot + AF[(size_t)bi * NFd + t];
  }
}

extern "C" void kernel_launch(void* const* d_in, const int* in_sizes, int n_in,
                              void* d_out, int out_size, void* d_ws, size_t ws_size,
                              hipStream_t stream) {
  const float* AF   = (const float*)d_in[0];
  const float* DM   = (const float*)d_in[1];
  const float* MASK = (const float*)d_in[2];
  const float* Wcf  = (const float*)d_in[3];
  const float* Wdf  = (const float*)d_in[4];
  const float* Wfc  = (const float*)d_in[5];
  const float* bcf  = (const float*)d_in[6];
  const float* bdf  = (const float*)d_in[7];
  float* out = (float*)d_out;

  float*  atomh = (float*)d_ws;                                   // 512 KB
  ushort* wdfp  = (ushort*)((char*)d_ws + 524288);                // 16 KB (K padded to 128)
  ushort* wfcp  = (ushort*)((char*)d_ws + 524288 + 16384);        // 8 KB

  prep_kernel<<<560, 256, 0, stream>>>(AF, Wcf, bcf, Wdf, Wfc, atomh, wdfp, wfcp);
  dtnn_main_kernel<<<Bsz * Nn, 256, 0, stream>>>(AF, DM, MASK, bdf, atomh, wdfp, wfcp, out);
}

// Round 6
// 35.843 us; speedup vs baseline: 1.7467x; 1.1455x over previous
//
#include <hip/hip_runtime.h>
#include <hip/hip_bf16.h>

#define Bsz 16
#define Nn  128
#define NFd 64
#define NDd 100
#define NHd 64

typedef __attribute__((ext_vector_type(8))) short bf16x8;
typedef __attribute__((ext_vector_type(4))) float f32x4;

__device__ __forceinline__ short f2bf(float f) {
  return (short)__builtin_bit_cast(ushort, __float2bfloat16(f));
}

__device__ __forceinline__ float fast_tanh(float x) {
  // tanh(x) = 1 - 2/(exp(2x)+1); exact at +/-inf, ~1ulp rcp error (<< bf16 noise)
  float e = __expf(2.0f * x);
  return 1.0f - 2.0f * __builtin_amdgcn_rcpf(e + 1.0f);
}

// async global->LDS DMA: LDS dest = uniform base + lane*size; global src per-lane
__device__ __forceinline__ void glds16(const float* g, float* l) {
  __builtin_amdgcn_global_load_lds(
      (const __attribute__((address_space(1))) void*)g,
      (__attribute__((address_space(3))) void*)l, 16, 0, 0);
}
__device__ __forceinline__ void glds4(const float* g, float* l) {
  __builtin_amdgcn_global_load_lds(
      (const __attribute__((address_space(1))) void*)g,
      (__attribute__((address_space(3))) void*)l, 4, 0, 0);
}

// ---------------- prep kernel ----------------
// blocks [0,512):    atomh[b,j,h] = b_cf[h] + sum_f AF[b,j,f]*W_cf[f,h]  (f32 -> ws)
// blocks [512,544):  pack W_df -> bf16 MFMA-B fragments, K zero-padded to 128
// blocks [544,560):  pack W_fc -> bf16 MFMA-B fragments (K=64)
// blocks [560,1072): out init: out = atom_features (main kernel atomically adds)
__global__ __launch_bounds__(256) void prep_kernel(
    const float* __restrict__ AF, const float* __restrict__ Wcf,
    const float* __restrict__ bcf, const float* __restrict__ Wdf,
    const float* __restrict__ Wfc, float* __restrict__ atomh,
    ushort* __restrict__ wdfp, ushort* __restrict__ wfcp,
    float* __restrict__ out) {
  int t = threadIdx.x;
  int blk = blockIdx.x;
  if (blk < 512) {
    int row = blk * 4 + (t >> 6);        // b*N + j
    int h = t & 63;
    const float* af = AF + (size_t)row * NFd;
    float a0 = 0.f, a1 = 0.f, a2 = 0.f, a3 = 0.f;
    #pragma unroll 4
    for (int f = 0; f < NFd; f += 4) {
      a0 += af[f + 0] * Wcf[(f + 0) * NHd + h];
      a1 += af[f + 1] * Wcf[(f + 1) * NHd + h];
      a2 += af[f + 2] * Wcf[(f + 2) * NHd + h];
      a3 += af[f + 3] * Wcf[(f + 3) * NHd + h];
    }
    atomh[(size_t)row * NHd + h] = bcf[h] + ((a0 + a1) + (a2 + a3));
  } else if (blk < 544) {
    // wdfp[(grp*64 + col)*8 + e] = bf16(Wdf[k = grp*8+e][col]), 0 if k >= 100
    int idx = (blk - 512) * 256 + t;     // [0, 8192)
    int e = idx & 7;
    int col = (idx >> 3) & 63;
    int grp = idx >> 9;
    int k = grp * 8 + e;
    float v = (k < NDd) ? Wdf[k * NHd + col] : 0.f;
    wdfp[idx] = (ushort)f2bf(v);
  } else if (blk < 560) {
    int idx = (blk - 544) * 256 + t;     // [0, 4096)
    int e = idx & 7;
    int col = (idx >> 3) & 63;
    int grp = idx >> 9;
    int k = grp * 8 + e;
    wfcp[idx] = (ushort)f2bf(Wfc[k * NFd + col]);
  } else {
    int idx = (blk - 560) * 256 + t;     // [0, 131072) = 2048*64
    out[idx] = AF[idx];
  }
}

// ---------------- main kernel: one block per (b,i,half), 4 independent waves ----------------
// Block (bi, half) covers j-rows [half*64, half*64+64). Wave w owns 16 rows:
// GLDS-stage its 6.4 KB f32 -> vmcnt(0) -> phase1 MFMA (K=100) -> gate ->
// bf16 gated tile written over its own staged LDS -> phase2 MFMA (K=64) ->
// tanh -> shfl-reduce -> atomicAdd 64 partials to out. No __syncthreads,
// no cross-wave data. 25.6 KB LDS -> 6 blocks/CU (24 waves).
__global__ __launch_bounds__(256, 6) void dtnn_main_kernel(
    const float* __restrict__ DM,
    const float* __restrict__ MASK,
    const float* __restrict__ bdf,
    const float* __restrict__ atomh,
    const ushort* __restrict__ wdfp,
    const ushort* __restrict__ wfcp,
    float* __restrict__ out) {
  __shared__ float stage[64 * 100];      // 25600 B, 4 wave-private 16-row slabs

  const int t    = threadIdx.x;
  const int blk  = blockIdx.x;           // [0, 4096)
  const int bi   = blk >> 1;             // b*N + i
  const int half = blk & 1;
  const int b    = bi >> 7;
  const int w    = t >> 6;               // wave 0..3
  const int lane = t & 63;
  const int p    = t & 15;
  const int q    = (t >> 4) & 3;

  const int jrow = half * 64 + w * 16;   // this wave's global j base

  // ---- async-stage this wave's 16 rows (6400 B) linearly into LDS ----
  const float* gsrc = DM + (size_t)bi * (Nn * NDd) + (size_t)jrow * NDd;
  float* lbase = stage + w * 1600;
  #pragma unroll
  for (int v = 0; v < 6; ++v)
    glds16(gsrc + v * 256 + lane * 4, lbase + v * 256);   // 6 x 1024 B
  glds4(gsrc + 1536 + lane, lbase + 1536);                // 256 B tail

  asm volatile("s_waitcnt vmcnt(0)" ::: "memory");
  __builtin_amdgcn_sched_barrier(0);

  const bf16x8* wdfv = reinterpret_cast<const bf16x8*>(wdfp);
  const bf16x8* wfcv = reinterpret_cast<const bf16x8*>(wfcp);

  // ---- phase 1: dist_h[j,h] = dm[j,:].W_df[:,h] + b_df[h], K=100 ----
  f32x4 acc[4];
  #pragma unroll
  for (int ht = 0; ht < 4; ++ht) {
    float bv = bdf[ht * 16 + p];
    acc[ht] = (f32x4){bv, bv, bv, bv};
  }

  const float* arow = stage + (w * 16 + p) * 100;
  #pragma unroll
  for (int ks = 0; ks < 3; ++ks) {       // k = [0,96)
    float4 x = *reinterpret_cast<const float4*>(arow + ks * 32 + q * 8);
    float4 y = *reinterpret_cast<const float4*>(arow + ks * 32 + q * 8 + 4);
    bf16x8 a;
    a[0] = f2bf(x.x); a[1] = f2bf(x.y); a[2] = f2bf(x.z); a[3] = f2bf(x.w);
    a[4] = f2bf(y.x); a[5] = f2bf(y.y); a[6] = f2bf(y.z); a[7] = f2bf(y.w);
    #pragma unroll
    for (int ht = 0; ht < 4; ++ht)
      acc[ht] = __builtin_amdgcn_mfma_f32_16x16x32_bf16(
          a, wdfv[(ks * 4 + q) * 64 + ht * 16 + p], acc[ht], 0, 0, 0);
  }
  {                                      // tail k = [96,100): only q==0 carries data
    bf16x8 a = (bf16x8){0, 0, 0, 0, 0, 0, 0, 0};
    if (q == 0) {
      float4 x = *reinterpret_cast<const float4*>(arow + 96);
      a[0] = f2bf(x.x); a[1] = f2bf(x.y); a[2] = f2bf(x.z); a[3] = f2bf(x.w);
    }
    #pragma unroll
    for (int ht = 0; ht < 4; ++ht)
      acc[ht] = __builtin_amdgcn_mfma_f32_16x16x32_bf16(
          a, wdfv[(12 + q) * 64 + ht * 16 + p], acc[ht], 0, 0, 0);
  }

  // ---- gate: acc[j][h] *= atomh[b,j,h]  (D: row j=jrow+4q+r, col h=16ht+p) ----
  const float* ap = atomh + ((size_t)(b * Nn + jrow + 4 * q)) * NHd + p;
  #pragma unroll
  for (int ht = 0; ht < 4; ++ht) {
    #pragma unroll
    for (int r = 0; r < 4; ++r) acc[ht][r] *= ap[r * NHd + ht * 16];
  }

  // ---- write gated (bf16, XOR-swizzled) over this wave's own staged slab ----
  ushort* gb = reinterpret_cast<ushort*>(lbase);
  #pragma unroll
  for (int r = 0; r < 4; ++r) {
    int rr = 4 * q + r;                  // local row 0..15
    int sw = (rr & 7) << 3;
    #pragma unroll
    for (int ht = 0; ht < 4; ++ht)
      gb[rr * 64 + ((ht * 16 + p) ^ sw)] = (ushort)f2bf(acc[ht][r]);
  }
  asm volatile("" ::: "memory");         // keep phase-2 reads below the writes

  // ---- phase 2: pre[j,f] = gated[j,:].W_fc[:,f], K=64 ----
  f32x4 acc2[4];
  #pragma unroll
  for (int ft = 0; ft < 4; ++ft) acc2[ft] = (f32x4){0.f, 0.f, 0.f, 0.f};

  #pragma unroll
  for (int ks = 0; ks < 2; ++ks) {
    int h0 = (ks * 32 + q * 8) ^ ((p & 7) << 3);
    bf16x8 a2 = *reinterpret_cast<const bf16x8*>(&gb[p * 64 + h0]);
    #pragma unroll
    for (int ft = 0; ft < 4; ++ft)
      acc2[ft] = __builtin_amdgcn_mfma_f32_16x16x32_bf16(
          a2, wfcv[(ks * 4 + q) * 64 + ft * 16 + p], acc2[ft], 0, 0, 0);
  }

  // ---- mask, tanh, accumulate this wave's 16 rows ----
  float s[4] = {0.f, 0.f, 0.f, 0.f};
  #pragma unroll
  for (int r = 0; r < 4; ++r) {
    float m = MASK[(size_t)bi * Nn + jrow + 4 * q + r];
    #pragma unroll
    for (int ft = 0; ft < 4; ++ft) s[ft] += fast_tanh(acc2[ft][r] * m);
  }

  // ---- reduce over q (rows) in-wave, then atomic partial-add to out ----
  #pragma unroll
  for (int ft = 0; ft < 4; ++ft) {
    s[ft] += __shfl_xor(s[ft], 16, 64);
    s[ft] += __shfl_xor(s[ft], 32, 64);
  }
  if (q == 0) {
    #pragma unroll
    for (int ft = 0; ft < 4; ++ft)
      unsafeAtomicAdd(&out[(size_t)bi * NFd + ft * 16 + p], s[ft]);
  }
}

extern "C" void kernel_launch(void* const* d_in, const int* in_sizes, int n_in,
                              void* d_out, int out_size, void* d_ws, size_t ws_size,
                              hipStream_t stream) {
  const float* AF   = (const float*)d_in[0];
  const float* DM   = (const float*)d_in[1];
  const float* MASK = (const float*)d_in[2];
  const float* Wcf  = (const float*)d_in[3];
  const float* Wdf  = (const float*)d_in[4];
  const float* Wfc  = (const float*)d_in[5];
  const float* bcf  = (const float*)d_in[6];
  const float* bdf  = (const float*)d_in[7];
  float* out = (float*)d_out;

  float*  atomh = (float*)d_ws;                                   // 512 KB
  ushort* wdfp  = (ushort*)((char*)d_ws + 524288);                // 16 KB (K padded to 128)
  ushort* wfcp  = (ushort*)((char*)d_ws + 524288 + 16384);        // 8 KB

  prep_kernel<<<1072, 256, 0, stream>>>(AF, Wcf, bcf, Wdf, Wfc, atomh, wdfp, wfcp, out);
  dtnn_main_kernel<<<2 * Bsz * Nn, 256, 0, stream>>>(DM, MASK, bdf, atomh, wdfp, wfcp, out);
}